// Round 6
// baseline (253.742 us; speedup 1.0000x reference)
//
#include <hip/hip_runtime.h>
#include <hip/hip_bf16.h>
#include <hip/hip_cooperative_groups.h>

namespace cg = cooperative_groups;

#define IN_CH   128
#define HIDDEN  256
#define H2DIM   128
#define KS1     17             // GEMM1 k-steps (K=544)
#define KS2     8              // GEMM2 k-steps (K=256)
#define NT1     16             // 256/16 n-tiles in GEMM1
#define NT2     8              // 128/16 n-tiles in GEMM2
#define FSTRIDE 552            // feats LDS k-stride (ushort, mult of 8)
#define H1S     264            // h1 overlay stride (ushort)
#define H2S     136            // h2 overlay stride (ushort)
#define H2OFF   16896          // h2 overlay offset (ushort) = 64*H1S
#define CAP     64             // adjacency-list cap (fallback if deg>CAP)
#define T1PACK  (NT1*KS1*64)   // 17408
#define T2PACK  (NT2*KS2*64)   // 4096

typedef short short8v __attribute__((ext_vector_type(8)));
typedef float f32x4   __attribute__((ext_vector_type(4)));

__device__ __forceinline__ ushort f2bf(float f) {
  union { float f; uint32_t u; } c; c.f = f;
  uint32_t u = c.u + 0x7FFFu + ((c.u >> 16) & 1u);   // RNE
  return (ushort)(u >> 16);
}
__device__ __forceinline__ float bf2f(ushort h) {
  union { uint32_t u; float f; } c; c.u = ((uint32_t)h) << 16;
  return c.f;
}
// packed RNE f32x2 -> bf16x2 via v_cvt_pk_bf16_f32
__device__ __forceinline__ uint32_t pk2(float a, float b) {
  __hip_bfloat162 h = __float22bfloat162_rn(make_float2(a, b));
  union { __hip_bfloat162 h; uint32_t u; } c; c.h = h;
  return c.u;
}
__device__ __forceinline__ uint4 pack8(float4 lo, float4 hi) {
  uint4 r;
  r.x = pk2(lo.x, lo.y); r.y = pk2(lo.z, lo.w);
  r.z = pk2(hi.x, hi.y); r.w = pk2(hi.z, hi.w);
  return r;
}

// ---------------- cooperative kernel: zero + pack + build + node lists ------
// phase 0: zero bitset, pack W1 (K-folded) / W2 to MFMA B-frag order
// phase 1: build adjacency bitset (atomicOr)
// phase 2: degree/invlog/invdeg/norm + sorted adjacency lists (wave per node)
__global__ void k_graph(const float* __restrict__ x, const int* __restrict__ ei,
                        const float* __restrict__ W1, const float* __restrict__ W2,
                        ushort* __restrict__ w1p, ushort* __restrict__ w2p,
                        uint32_t* __restrict__ bits,
                        float* __restrict__ invlog, float* __restrict__ invdeg,
                        int* __restrict__ deg, float* __restrict__ nrm,
                        ushort* __restrict__ adjl,
                        int N, int E, int roww, int nwords) {
  cg::grid_group grid = cg::this_grid();
  int t = blockIdx.x * blockDim.x + threadIdx.x;
  int nthr = gridDim.x * blockDim.x;

  // ---- phase 0a: zero bitset ----
  for (int i = t; i < nwords; i += nthr) bits[i] = 0u;

  // ---- phase 0b: pack weights ----
  // W1' rows: [0,128): A+E ; [128,256): B+E ; [256,512): C,D ; [512,516): scalars; pad 0
  if (t < T1PACK) {
    int l = t & 63;
    int rest = t >> 6;
    int ks = rest % KS1;
    int nt = rest / KS1;
    int n  = nt * 16 + (l & 15);
    int k0 = ks * 32 + (l >> 4) * 8;
    short8v v;
    #pragma unroll
    for (int j = 0; j < 8; ++j) {
      int k = k0 + j;
      float val;
      if (k < 128)      val = W1[(size_t)k * HIDDEN + n] + W1[(size_t)(512 + k) * HIDDEN + n];
      else if (k < 256) val = W1[(size_t)k * HIDDEN + n] + W1[(size_t)(384 + k) * HIDDEN + n];
      else if (k < 512) val = W1[(size_t)k * HIDDEN + n];
      else if (k < 516) val = W1[(size_t)(k + 128) * HIDDEN + n];   // rows 640..643
      else              val = 0.f;
      v[j] = (short)f2bf(val);
    }
    *(short8v*)(w1p + (size_t)t * 8) = v;
  } else if (t < T1PACK + T2PACK) {
    int t2 = t - T1PACK;
    int l = t2 & 63;
    int rest = t2 >> 6;
    int ks = rest % KS2;
    int nt = rest / KS2;
    int n  = nt * 16 + (l & 15);
    int k0 = ks * 32 + (l >> 4) * 8;
    short8v v;
    #pragma unroll
    for (int j = 0; j < 8; ++j)
      v[j] = (short)f2bf(W2[(size_t)(k0 + j) * H2DIM + n]);
    *(short8v*)(w2p + (size_t)t2 * 8) = v;
  }

  grid.sync();

  // ---- phase 1: build adjacency ----
  for (int e = t; e < E; e += nthr) {
    int u = ei[e];
    int v = ei[E + e];
    if (u != v)
      atomicOr((unsigned int*)&bits[(size_t)u * roww + (v >> 5)], 1u << (v & 31));
  }

  grid.sync();

  // ---- phase 2: node stats + lists (one wave per node) ----
  int wid = t >> 6, lane = t & 63, nwaves = nthr >> 6;
  for (int node = wid; node < N; node += nwaves) {
    const uint32_t* row = bits + (size_t)node * roww;
    uint32_t wd[4];
    int c = 0;
    #pragma unroll
    for (int j = 0; j < 4; ++j) { wd[j] = row[lane * 4 + j]; c += __popc(wd[j]); }
    int sum = c;
    #pragma unroll
    for (int off = 1; off < 64; off <<= 1) {
      int tt = __shfl_up(sum, off);
      if (lane >= off) sum += tt;
    }
    int excl = sum - c;
    int total = __shfl(sum, 63);
    ushort* lst = adjl + (size_t)node * CAP;
    int pos = excl;
    #pragma unroll
    for (int j = 0; j < 4; ++j) {
      uint32_t m = wd[j];
      int base = (lane * 4 + j) * 32;
      while (m) {
        int b = __ffs(m) - 1;
        if (pos < CAP) lst[pos] = (ushort)(base + b);
        ++pos;
        m &= m - 1;
      }
    }
    float2 xa = *(const float2*)(x + (size_t)node * IN_CH + 2 * lane);
    float ss = xa.x * xa.x + xa.y * xa.y;
    #pragma unroll
    for (int off = 32; off; off >>= 1) ss += __shfl_xor(ss, off);
    if (lane == 0) {
      deg[node] = total;
      float d = (float)total;
      invlog[node] = (total > 1) ? 1.0f / logf(d) : 0.0f;
      invdeg[node] = (total > 0) ? 1.0f / d : 0.0f;
      nrm[node] = sqrtf(ss);
    }
  }
}

// ---------------- main kernel: fused features + pair stats + MFMA MLP ------
// 64 pairs/block, 512 threads (8 waves). bf16 MFMA 16x16x32, fp32 accum.
__global__ __launch_bounds__(512, 4) void k_mlp5(
    const float* __restrict__ x, const int* __restrict__ pairs,
    const uint32_t* __restrict__ bits, int roww,
    const int* __restrict__ deg, const float* __restrict__ nrm,
    const float* __restrict__ invlog, const float* __restrict__ invdeg,
    const ushort* __restrict__ adjl,
    const ushort* __restrict__ w1p, const float* __restrict__ b1,
    const ushort* __restrict__ w2p, const float* __restrict__ b2,
    const float* __restrict__ W3, const float* __restrict__ b3,
    float* __restrict__ out, int P)
{
  __shared__ ushort feats[64 * FSTRIDE];   // 69 KB; h1/h2 overlay after dead
  __shared__ int us[64], vs[64];

  int tid = threadIdx.x;
  int pb = blockIdx.x * 64;
  int w  = tid >> 6, l = tid & 63;

  if (tid < 64) {
    int2 pr = ((const int2*)pairs)[pb + tid];
    us[tid] = pr.x; vs[tid] = pr.y;
  }
  __syncthreads();

  // ---- stats metadata prefetch (issued early; hides under feature build) ----
  int pu[8], pv[8];
  #pragma unroll
  for (int pp = 0; pp < 8; ++pp) { pu[pp] = us[w * 8 + pp]; pv[pp] = vs[w * 8 + pp]; }
  int du[8], dv[8];
  #pragma unroll
  for (int pp = 0; pp < 8; ++pp) { du[pp] = deg[pu[pp]]; dv[pp] = deg[pv[pp]]; }
  int nbu[8], nbv[8];
  #pragma unroll
  for (int pp = 0; pp < 8; ++pp) {
    nbu[pp] = adjl[(size_t)pu[pp] * CAP + l];
    nbv[pp] = adjl[(size_t)pv[pp] * CAP + l];
  }

  // ---- feature build: 8 lanes per pair, all 8 pairs of this wave in one pass
  {
    int pg = l >> 3, g = l & 7;              // pair-in-group, channel group (16ch)
    int p = w * 8 + pg;
    int u = us[p], v = vs[p];
    const float* xu = x + (size_t)u * IN_CH + g * 16;
    const float* xv = x + (size_t)v * IN_CH + g * 16;
    float4 a0 = *(const float4*)(xu + 0),  a1 = *(const float4*)(xu + 4);
    float4 a2 = *(const float4*)(xu + 8),  a3 = *(const float4*)(xu + 12);
    float4 b0 = *(const float4*)(xv + 0),  b1v = *(const float4*)(xv + 4);
    float4 b2v = *(const float4*)(xv + 8), b3v = *(const float4*)(xv + 12);
    ushort* fpR = feats + p * FSTRIDE;
    ushort* fp  = fpR + g * 16;
    *(uint4*)(fp)       = pack8(a0, a1);
    *(uint4*)(fp + 8)   = pack8(a2, a3);
    *(uint4*)(fp + 128) = pack8(b0, b1v);
    *(uint4*)(fp + 136) = pack8(b2v, b3v);
    float4 c0, c1, c2, c3, d0, d1, d2, d3;
    c0.x=a0.x*b0.x;  c0.y=a0.y*b0.y;  c0.z=a0.z*b0.z;  c0.w=a0.w*b0.w;
    c1.x=a1.x*b1v.x; c1.y=a1.y*b1v.y; c1.z=a1.z*b1v.z; c1.w=a1.w*b1v.w;
    c2.x=a2.x*b2v.x; c2.y=a2.y*b2v.y; c2.z=a2.z*b2v.z; c2.w=a2.w*b2v.w;
    c3.x=a3.x*b3v.x; c3.y=a3.y*b3v.y; c3.z=a3.z*b3v.z; c3.w=a3.w*b3v.w;
    d0.x=fabsf(a0.x-b0.x);  d0.y=fabsf(a0.y-b0.y);  d0.z=fabsf(a0.z-b0.z);  d0.w=fabsf(a0.w-b0.w);
    d1.x=fabsf(a1.x-b1v.x); d1.y=fabsf(a1.y-b1v.y); d1.z=fabsf(a1.z-b1v.z); d1.w=fabsf(a1.w-b1v.w);
    d2.x=fabsf(a2.x-b2v.x); d2.y=fabsf(a2.y-b2v.y); d2.z=fabsf(a2.z-b2v.z); d2.w=fabsf(a2.w-b2v.w);
    d3.x=fabsf(a3.x-b3v.x); d3.y=fabsf(a3.y-b3v.y); d3.z=fabsf(a3.z-b3v.z); d3.w=fabsf(a3.w-b3v.w);
    *(uint4*)(fp + 256) = pack8(c0, c1);
    *(uint4*)(fp + 264) = pack8(c2, c3);
    *(uint4*)(fp + 384) = pack8(d0, d1);
    *(uint4*)(fp + 392) = pack8(d2, d3);
    float suv = c0.x+c0.y+c0.z+c0.w + c1.x+c1.y+c1.z+c1.w
              + c2.x+c2.y+c2.z+c2.w + c3.x+c3.y+c3.z+c3.w;
    suv += __shfl_xor(suv, 1);
    suv += __shfl_xor(suv, 2);
    suv += __shfl_xor(suv, 4);
    if (g == 0) {
      float cosv = suv / fmaxf(nrm[u] * nrm[v], 1e-8f);
      fpR[512] = f2bf(cosv);
    }
    if (g < 7) {   // zero pad 516..543
      *(uint32_t*)(fpR + 516 + 4 * g) = 0u;
      *(uint32_t*)(fpR + 516 + 4 * g + 2) = 0u;
    }
  }

  // ---- pair stats: all 8 probe chains in flight, then cheap ballot phases ----
  {
    int dmin[8], nbs[8];
    uint32_t wrd[8];
    bool fall = false;
    #pragma unroll
    for (int pp = 0; pp < 8; ++pp) {
      bool ule = du[pp] <= dv[pp];
      dmin[pp] = ule ? du[pp] : dv[pp];
      int o   = ule ? pv[pp] : pu[pp];
      int nb  = (ule ? nbu[pp] : nbv[pp]) & 8191;    // clamp garbage beyond deg
      nbs[pp] = nb;
      wrd[pp] = bits[(size_t)o * roww + (nb >> 5)];  // 8 independent loads in flight
      fall |= (dmin[pp] > CAP);
    }
    if (!fall) {          // wave-uniform (du/dv uniform across lanes)
      #pragma unroll
      for (int pp = 0; pp < 8; ++pp) {
        bool h = (l < dmin[pp]) && ((wrd[pp] >> (nbs[pp] & 31)) & 1u);
        unsigned long long mask = __ballot(h);
        float cnv = (float)__popcll(mask);
        float aa = 0.f, ra = 0.f;
        if (mask) {
          float il = 0.f, ig = 0.f;
          if (h) { il = invlog[nbs[pp]]; ig = invdeg[nbs[pp]]; }
          while (mask) {
            int ln = __ffsll(mask) - 1;
            aa += __shfl(il, ln);
            ra += __shfl(ig, ln);
            mask &= mask - 1;
          }
        }
        if (l == 0) {
          ushort* fpR = feats + (w * 8 + pp) * FSTRIDE;
          fpR[513] = f2bf(cnv);
          fpR[514] = f2bf(aa);
          fpR[515] = f2bf(ra);
        }
      }
    } else {              // ~never: some deg>CAP, do exact bitset-AND per pair
      for (int pp = 0; pp < 8; ++pp) {
        int u = pu[pp], v = pv[pp];
        float cnL = 0.f, aaL = 0.f, raL = 0.f;
        const uint32_t* ru = bits + (size_t)u * roww;
        const uint32_t* rv = bits + (size_t)v * roww;
        for (int wd = l; wd < roww; wd += 64) {
          uint32_t c = ru[wd] & rv[wd];
          cnL += (float)__popc(c);
          while (c) {
            int bb = __ffs(c) - 1;
            int idx = wd * 32 + bb;
            aaL += invlog[idx]; raL += invdeg[idx];
            c &= c - 1;
          }
        }
        #pragma unroll
        for (int off = 32; off; off >>= 1) {
          cnL += __shfl_xor(cnL, off);
          aaL += __shfl_xor(aaL, off);
          raL += __shfl_xor(raL, off);
        }
        if (l == 0) {
          ushort* fpR = feats + (w * 8 + pp) * FSTRIDE;
          fpR[513] = f2bf(cnL);
          fpR[514] = f2bf(aaL);
          fpR[515] = f2bf(raL);
        }
      }
    }
  }
  __syncthreads();

  int lr = l & 15;         // A row / B,C col within tile
  int lk = l >> 4;         // k-group (and C row group)

  // ---- GEMM1: feats[64 x 544] @ W1'[544 x 256]; wave w: n-tiles {2w,2w+1} ----
  f32x4 acc[4][2];
  #pragma unroll
  for (int m = 0; m < 4; ++m)
    #pragma unroll
    for (int i = 0; i < 2; ++i) acc[m][i] = (f32x4){0.f, 0.f, 0.f, 0.f};

  const ushort* aB = feats + lr * FSTRIDE + lk * 8;
  const ushort* bW = w1p + (size_t)(w * 2) * KS1 * 512 + l * 8;

  short8v bf[2][2];
  #pragma unroll
  for (int i = 0; i < 2; ++i)
    bf[0][i] = *(const short8v*)(bW + (size_t)(i * KS1) * 512);

  #pragma unroll
  for (int ks = 0; ks < KS1; ++ks) {
    int cur = ks & 1, nxt = cur ^ 1;
    if (ks + 1 < KS1) {
      #pragma unroll
      for (int i = 0; i < 2; ++i)
        bf[nxt][i] = *(const short8v*)(bW + (size_t)(i * KS1 + ks + 1) * 512);
    }
    short8v am[4];
    #pragma unroll
    for (int m = 0; m < 4; ++m)
      am[m] = *(const short8v*)(aB + m * 16 * FSTRIDE + ks * 32);
    #pragma unroll
    for (int i = 0; i < 2; ++i)
      #pragma unroll
      for (int m = 0; m < 4; ++m)
        acc[m][i] = __builtin_amdgcn_mfma_f32_16x16x32_bf16(am[m], bf[cur][i], acc[m][i], 0, 0, 0);
  }

  uint32_t h1r[2][8];
  #pragma unroll
  for (int i = 0; i < 2; ++i) {
    float bias = b1[(w * 2 + i) * 16 + lr];
    #pragma unroll
    for (int m = 0; m < 4; ++m) {
      float v0 = fmaxf(acc[m][i][0] + bias, 0.f);
      float v1 = fmaxf(acc[m][i][1] + bias, 0.f);
      float v2 = fmaxf(acc[m][i][2] + bias, 0.f);
      float v3 = fmaxf(acc[m][i][3] + bias, 0.f);
      h1r[i][m * 2]     = pk2(v0, v1);
      h1r[i][m * 2 + 1] = pk2(v2, v3);
    }
  }
  __syncthreads();   // feats fully consumed

  ushort* h1 = feats;   // [row*H1S + col]
  #pragma unroll
  for (int i = 0; i < 2; ++i) {
    int col = (w * 2 + i) * 16 + lr;
    #pragma unroll
    for (int m = 0; m < 4; ++m) {
      int row0 = m * 16 + lk * 4;
      h1[(row0)     * H1S + col] = (ushort)(h1r[i][m * 2]);
      h1[(row0 + 1) * H1S + col] = (ushort)(h1r[i][m * 2] >> 16);
      h1[(row0 + 2) * H1S + col] = (ushort)(h1r[i][m * 2 + 1]);
      h1[(row0 + 3) * H1S + col] = (ushort)(h1r[i][m * 2 + 1] >> 16);
    }
  }
  __syncthreads();

  // ---- GEMM2: h1[64 x 256] @ W2[256 x 128]; wave w owns n-tile w ----
  f32x4 acc2[4];
  #pragma unroll
  for (int m = 0; m < 4; ++m) acc2[m] = (f32x4){0.f, 0.f, 0.f, 0.f};

  const ushort* aB2 = h1 + lr * H1S + lk * 8;
  const ushort* bW2 = w2p + (size_t)w * KS2 * 512 + l * 8;

  short8v b2f[2];
  b2f[0] = *(const short8v*)(bW2);

  #pragma unroll
  for (int ks = 0; ks < KS2; ++ks) {
    int cur = ks & 1, nxt = cur ^ 1;
    if (ks + 1 < KS2)
      b2f[nxt] = *(const short8v*)(bW2 + (size_t)(ks + 1) * 512);
    #pragma unroll
    for (int m = 0; m < 4; ++m) {
      short8v am = *(const short8v*)(aB2 + m * 16 * H1S + ks * 32);
      acc2[m] = __builtin_amdgcn_mfma_f32_16x16x32_bf16(am, b2f[cur], acc2[m], 0, 0, 0);
    }
  }

  ushort* h2 = feats + H2OFF;
  {
    int col = w * 16 + lr;
    float bias = b2[col];
    #pragma unroll
    for (int m = 0; m < 4; ++m) {
      int row0 = m * 16 + lk * 4;
      #pragma unroll
      for (int r = 0; r < 4; ++r)
        h2[(row0 + r) * H2S + col] = f2bf(fmaxf(acc2[m][r] + bias, 0.f));
    }
  }
  __syncthreads();

  // ---- GEMM3: h2[64 x 128] @ W3[128 x 1] ----
  {
    int p = tid >> 3, g = tid & 7;
    const ushort* hp = h2 + p * H2S + g * 16;
    float s = 0.f;
    #pragma unroll
    for (int j = 0; j < 16; ++j) s += bf2f(hp[j]) * W3[g * 16 + j];
    s += __shfl_down(s, 4, 8);
    s += __shfl_down(s, 2, 8);
    s += __shfl_down(s, 1, 8);
    if (g == 0) out[pb + p] = s + b3[0];
  }
}

extern "C" void kernel_launch(void* const* d_in, const int* in_sizes, int n_in,
                              void* d_out, int out_size, void* d_ws, size_t ws_size,
                              hipStream_t stream) {
  const float* x     = (const float*)d_in[0];
  const int*   ei    = (const int*)d_in[1];
  const int*   pairs = (const int*)d_in[2];
  const float* W1    = (const float*)d_in[3];
  const float* b1    = (const float*)d_in[4];
  const float* W2    = (const float*)d_in[5];
  const float* b2    = (const float*)d_in[6];
  const float* W3    = (const float*)d_in[7];
  const float* b3    = (const float*)d_in[8];
  float* out = (float*)d_out;

  int N = in_sizes[0] / IN_CH;       // 8192
  int E = in_sizes[1] / 2;           // 262144
  int P = in_sizes[2] / 2;           // 65536
  int roww = (N + 31) >> 5;          // 256

  char* wsb = (char*)d_ws;
  uint32_t* bits = (uint32_t*)wsb;                       size_t off = (size_t)N * roww * 4;
  float* invlog  = (float*)(wsb + off);                  off += (size_t)N * 4;
  float* invdeg  = (float*)(wsb + off);                  off += (size_t)N * 4;
  int*   deg     = (int*)(wsb + off);                    off += (size_t)N * 4;
  float* nrm     = (float*)(wsb + off);                  off += (size_t)N * 4;
  ushort* adjl   = (ushort*)(wsb + off);                 off += (size_t)N * CAP * 2;
  ushort* w1pack = (ushort*)(wsb + off);                 off += (size_t)T1PACK * 8 * 2;
  ushort* w2pack = (ushort*)(wsb + off);                 off += (size_t)T2PACK * 8 * 2;

  int nwords = N * roww;
  void* gargs[] = { (void*)&x, (void*)&ei, (void*)&W1, (void*)&W2,
                    (void*)&w1pack, (void*)&w2pack, (void*)&bits,
                    (void*)&invlog, (void*)&invdeg, (void*)&deg, (void*)&nrm,
                    (void*)&adjl, (void*)&N, (void*)&E, (void*)&roww, (void*)&nwords };
  hipLaunchCooperativeKernel((void*)k_graph, dim3(1024), dim3(256), gargs, 0, stream);
  k_mlp5<<<P / 64, 512, 0, stream>>>(x, pairs, bits, roww, deg, nrm, invlog, invdeg, adjl,
                                     w1pack, b1, w2pack, b2, W3, b3, out, P);
}

// Round 7
// 81.224 us; speedup vs baseline: 3.1240x; 3.1240x over previous
//
#include <hip/hip_runtime.h>
#include <hip/hip_bf16.h>

#define IN_CH   128
#define HIDDEN  256
#define H2DIM   128
#define KS1     17             // GEMM1 k-steps (K=544)
#define KS2     8              // GEMM2 k-steps (K=256)
#define NT1     16             // 256/16 n-tiles in GEMM1
#define NT2     8              // 128/16 n-tiles in GEMM2
#define FSTRIDE 552            // feats LDS k-stride (ushort, mult of 8)
#define H1S     264            // h1 overlay stride (ushort)
#define H2S     136            // h2 overlay stride (ushort)
#define H2OFF   16896          // h2 overlay offset (ushort) = 64*H1S
#define CAP     64             // adjacency-list cap (fallback if deg>CAP)
#define T1PACK  (NT1*KS1*64)   // 17408
#define T2PACK  (NT2*KS2*64)   // 4096

typedef short short8v __attribute__((ext_vector_type(8)));
typedef float f32x4   __attribute__((ext_vector_type(4)));

__device__ __forceinline__ ushort f2bf(float f) {
  union { float f; uint32_t u; } c; c.f = f;
  uint32_t u = c.u + 0x7FFFu + ((c.u >> 16) & 1u);   // RNE
  return (ushort)(u >> 16);
}
__device__ __forceinline__ float bf2f(ushort h) {
  union { uint32_t u; float f; } c; c.u = ((uint32_t)h) << 16;
  return c.f;
}
// packed RNE f32x2 -> bf16x2 via v_cvt_pk_bf16_f32
__device__ __forceinline__ uint32_t pk2(float a, float b) {
  __hip_bfloat162 h = __float22bfloat162_rn(make_float2(a, b));
  union { __hip_bfloat162 h; uint32_t u; } c; c.h = h;
  return c.u;
}
__device__ __forceinline__ uint4 pack8(float4 lo, float4 hi) {
  uint4 r;
  r.x = pk2(lo.x, lo.y); r.y = pk2(lo.z, lo.w);
  r.z = pk2(hi.x, hi.y); r.w = pk2(hi.z, hi.w);
  return r;
}

// ---------------- kernel 1: zero bitset + pack W1(K-folded)/W2 ----------------
// W1' rows: [0,128): A+E ; [128,256): B+E ; [256,512): C,D ; [512,516): scalars; pad 0
__global__ void k_prep(const float* __restrict__ W1, const float* __restrict__ W2,
                       ushort* __restrict__ w1p, ushort* __restrict__ w2p,
                       uint32_t* __restrict__ bits, int nwords) {
  int t = blockIdx.x * blockDim.x + threadIdx.x;
  if (t < T1PACK) {
    int l = t & 63;
    int rest = t >> 6;
    int ks = rest % KS1;
    int nt = rest / KS1;
    int n  = nt * 16 + (l & 15);
    int k0 = ks * 32 + (l >> 4) * 8;
    short8v v;
    #pragma unroll
    for (int j = 0; j < 8; ++j) {
      int k = k0 + j;
      float val;
      if (k < 128)      val = W1[(size_t)k * HIDDEN + n] + W1[(size_t)(512 + k) * HIDDEN + n];
      else if (k < 256) val = W1[(size_t)k * HIDDEN + n] + W1[(size_t)(384 + k) * HIDDEN + n];
      else if (k < 512) val = W1[(size_t)k * HIDDEN + n];
      else if (k < 516) val = W1[(size_t)(k + 128) * HIDDEN + n];   // rows 640..643
      else              val = 0.f;
      v[j] = (short)f2bf(val);
    }
    *(short8v*)(w1p + (size_t)t * 8) = v;
  } else if (t < T1PACK + T2PACK) {
    int t2 = t - T1PACK;
    int l = t2 & 63;
    int rest = t2 >> 6;
    int ks = rest % KS2;
    int nt = rest / KS2;
    int n  = nt * 16 + (l & 15);
    int k0 = ks * 32 + (l >> 4) * 8;
    short8v v;
    #pragma unroll
    for (int j = 0; j < 8; ++j)
      v[j] = (short)f2bf(W2[(size_t)(k0 + j) * H2DIM + n]);
    *(short8v*)(w2p + (size_t)t2 * 8) = v;
  }
  int stride = gridDim.x * blockDim.x;
  for (int i = t; i < nwords; i += stride) bits[i] = 0u;
}

// ---------------- kernel 2: build adjacency bitset ----------------
__global__ void k_build_adj(const int* __restrict__ ei, int E, int roww,
                            uint32_t* __restrict__ bits) {
  int e = blockIdx.x * blockDim.x + threadIdx.x;
  if (e >= E) return;
  int u = ei[e];
  int v = ei[E + e];
  if (u == v) return;
  atomicOr((unsigned int*)&bits[(size_t)u * roww + (v >> 5)], 1u << (v & 31));
}

// ---------------- kernel 3: degree stats + adjacency lists + node norms ----
__global__ void k_node_lists(const uint32_t* __restrict__ bits, const float* __restrict__ x,
                             int nnodes, int roww,
                             float* __restrict__ invlog, float* __restrict__ invdeg,
                             int* __restrict__ deg, float* __restrict__ nrm,
                             ushort* __restrict__ adjl) {
  int node = blockIdx.x * (blockDim.x >> 6) + (threadIdx.x >> 6);
  int lane = threadIdx.x & 63;
  if (node >= nnodes) return;
  const uint32_t* row = bits + (size_t)node * roww;
  uint32_t wd[4];
  int c = 0;
  #pragma unroll
  for (int j = 0; j < 4; ++j) { wd[j] = row[lane * 4 + j]; c += __popc(wd[j]); }
  int sum = c;
  #pragma unroll
  for (int off = 1; off < 64; off <<= 1) {
    int t = __shfl_up(sum, off);
    if (lane >= off) sum += t;
  }
  int excl = sum - c;
  int total = __shfl(sum, 63);
  ushort* lst = adjl + (size_t)node * CAP;
  int pos = excl;
  #pragma unroll
  for (int j = 0; j < 4; ++j) {
    uint32_t m = wd[j];
    int base = (lane * 4 + j) * 32;
    while (m) {
      int b = __ffs(m) - 1;
      if (pos < CAP) lst[pos] = (ushort)(base + b);
      ++pos;
      m &= m - 1;
    }
  }
  float2 xa = *(const float2*)(x + (size_t)node * IN_CH + 2 * lane);
  float ss = xa.x * xa.x + xa.y * xa.y;
  #pragma unroll
  for (int off = 32; off; off >>= 1) ss += __shfl_xor(ss, off);
  if (lane == 0) {
    deg[node] = total;
    float d = (float)total;
    invlog[node] = (total > 1) ? 1.0f / logf(d) : 0.0f;
    invdeg[node] = (total > 0) ? 1.0f / d : 0.0f;
    nrm[node] = sqrtf(ss);
  }
}

// ---------------- kernel 4: fused features + pair stats + MFMA MLP ----------
// 128 pairs/block as 2 tiles of 64; 512 threads (8 waves). Tile t+1's global
// gathers are issued during tile t's GEMM2/3 and consumed after GEMM3.
__global__ __launch_bounds__(512, 4) void k_mlp6(
    const float* __restrict__ x, const int* __restrict__ pairs,
    const uint32_t* __restrict__ bits, int roww,
    const int* __restrict__ deg, const float* __restrict__ nrm,
    const float* __restrict__ invlog, const float* __restrict__ invdeg,
    const ushort* __restrict__ adjl,
    const ushort* __restrict__ w1p, const float* __restrict__ b1,
    const ushort* __restrict__ w2p, const float* __restrict__ b2,
    const float* __restrict__ W3, const float* __restrict__ b3,
    float* __restrict__ out, int P)
{
  __shared__ ushort feats[64 * FSTRIDE];   // 69 KB; h1/h2 overlay after dead
  __shared__ int us[128], vs[128];

  int tid = threadIdx.x;
  int pb = blockIdx.x * 128;
  int w  = tid >> 6, l = tid & 63;
  int pg = l >> 3, g = l & 7;        // feature-build mapping: 8 lanes per pair
  int lr = l & 15;                   // MFMA A row / B,C col within tile
  int lk = l >> 4;                   // MFMA k-group / C row group

  if (tid < 128) {
    int2 pr = ((const int2*)pairs)[pb + tid];
    us[tid] = pr.x; vs[tid] = pr.y;
  }
  __syncthreads();

  // gather registers (persist across the tile loop)
  float4 ga[4], gb[4];
  float gnu, gnv;
  int sdmin[8], snbs[8];
  uint32_t swrd[8];
  bool sfall;

  // ---- GATHER(t): issue all global loads for tile t into registers ----
  #define GATHER(t)                                                            \
  {                                                                            \
    int p = (t) * 64 + w * 8 + pg;                                             \
    int u = us[p], v = vs[p];                                                  \
    const float* xu = x + (size_t)u * IN_CH + g * 16;                          \
    const float* xv = x + (size_t)v * IN_CH + g * 16;                          \
    ga[0] = *(const float4*)(xu + 0);  ga[1] = *(const float4*)(xu + 4);       \
    ga[2] = *(const float4*)(xu + 8);  ga[3] = *(const float4*)(xu + 12);      \
    gb[0] = *(const float4*)(xv + 0);  gb[1] = *(const float4*)(xv + 4);       \
    gb[2] = *(const float4*)(xv + 8);  gb[3] = *(const float4*)(xv + 12);      \
    gnu = nrm[u]; gnv = nrm[v];                                                \
    sfall = false;                                                             \
    _Pragma("unroll")                                                          \
    for (int pp = 0; pp < 8; ++pp) {                                           \
      int ps_ = (t) * 64 + w * 8 + pp;                                         \
      int uu = us[ps_], vv = vs[ps_];                                          \
      int du = deg[uu], dv = deg[vv];                                          \
      int nu = adjl[(size_t)uu * CAP + l];                                     \
      int nv = adjl[(size_t)vv * CAP + l];                                     \
      bool ule = du <= dv;                                                     \
      sdmin[pp] = ule ? du : dv;                                               \
      int o  = ule ? vv : uu;                                                  \
      int nb = (ule ? nu : nv) & 8191;                                         \
      snbs[pp] = nb;                                                           \
      swrd[pp] = bits[(size_t)o * roww + (nb >> 5)];                           \
      sfall |= (sdmin[pp] > CAP);                                              \
    }                                                                          \
  }

  // ---- WRITE_FEATS(t): bf16-pack features into LDS + stats ballot ----
  #define WRITE_FEATS(t)                                                       \
  {                                                                            \
    ushort* fpR = feats + (w * 8 + pg) * FSTRIDE;                              \
    ushort* fp  = fpR + g * 16;                                                \
    *(uint4*)(fp)       = pack8(ga[0], ga[1]);                                 \
    *(uint4*)(fp + 8)   = pack8(ga[2], ga[3]);                                 \
    *(uint4*)(fp + 128) = pack8(gb[0], gb[1]);                                 \
    *(uint4*)(fp + 136) = pack8(gb[2], gb[3]);                                 \
    float4 c0, c1, c2, c3, d0, d1, d2, d3;                                     \
    c0.x=ga[0].x*gb[0].x; c0.y=ga[0].y*gb[0].y; c0.z=ga[0].z*gb[0].z; c0.w=ga[0].w*gb[0].w; \
    c1.x=ga[1].x*gb[1].x; c1.y=ga[1].y*gb[1].y; c1.z=ga[1].z*gb[1].z; c1.w=ga[1].w*gb[1].w; \
    c2.x=ga[2].x*gb[2].x; c2.y=ga[2].y*gb[2].y; c2.z=ga[2].z*gb[2].z; c2.w=ga[2].w*gb[2].w; \
    c3.x=ga[3].x*gb[3].x; c3.y=ga[3].y*gb[3].y; c3.z=ga[3].z*gb[3].z; c3.w=ga[3].w*gb[3].w; \
    d0.x=fabsf(ga[0].x-gb[0].x); d0.y=fabsf(ga[0].y-gb[0].y); d0.z=fabsf(ga[0].z-gb[0].z); d0.w=fabsf(ga[0].w-gb[0].w); \
    d1.x=fabsf(ga[1].x-gb[1].x); d1.y=fabsf(ga[1].y-gb[1].y); d1.z=fabsf(ga[1].z-gb[1].z); d1.w=fabsf(ga[1].w-gb[1].w); \
    d2.x=fabsf(ga[2].x-gb[2].x); d2.y=fabsf(ga[2].y-gb[2].y); d2.z=fabsf(ga[2].z-gb[2].z); d2.w=fabsf(ga[2].w-gb[2].w); \
    d3.x=fabsf(ga[3].x-gb[3].x); d3.y=fabsf(ga[3].y-gb[3].y); d3.z=fabsf(ga[3].z-gb[3].z); d3.w=fabsf(ga[3].w-gb[3].w); \
    *(uint4*)(fp + 256) = pack8(c0, c1);                                       \
    *(uint4*)(fp + 264) = pack8(c2, c3);                                       \
    *(uint4*)(fp + 384) = pack8(d0, d1);                                       \
    *(uint4*)(fp + 392) = pack8(d2, d3);                                       \
    float suv = c0.x+c0.y+c0.z+c0.w + c1.x+c1.y+c1.z+c1.w                      \
              + c2.x+c2.y+c2.z+c2.w + c3.x+c3.y+c3.z+c3.w;                     \
    suv += __shfl_xor(suv, 1);                                                 \
    suv += __shfl_xor(suv, 2);                                                 \
    suv += __shfl_xor(suv, 4);                                                 \
    if (g == 0) fpR[512] = f2bf(suv / fmaxf(gnu * gnv, 1e-8f));                \
    if (g < 7) {                                                               \
      *(uint32_t*)(fpR + 516 + 4 * g) = 0u;                                    \
      *(uint32_t*)(fpR + 516 + 4 * g + 2) = 0u;                                \
    }                                                                          \
    if (!sfall) {                                                              \
      _Pragma("unroll")                                                        \
      for (int pp = 0; pp < 8; ++pp) {                                         \
        bool h = (l < sdmin[pp]) && ((swrd[pp] >> (snbs[pp] & 31)) & 1u);      \
        unsigned long long mask = __ballot(h);                                 \
        float cnv = (float)__popcll(mask);                                     \
        float aa = 0.f, ra = 0.f;                                              \
        if (mask) {                                                            \
          float il = 0.f, ig = 0.f;                                            \
          if (h) { il = invlog[snbs[pp]]; ig = invdeg[snbs[pp]]; }             \
          while (mask) {                                                       \
            int ln = __ffsll(mask) - 1;                                        \
            aa += __shfl(il, ln);                                              \
            ra += __shfl(ig, ln);                                              \
            mask &= mask - 1;                                                  \
          }                                                                    \
        }                                                                      \
        if (l == 0) {                                                          \
          ushort* fq = feats + (w * 8 + pp) * FSTRIDE;                         \
          fq[513] = f2bf(cnv); fq[514] = f2bf(aa); fq[515] = f2bf(ra);         \
        }                                                                      \
      }                                                                        \
    } else {                                                                   \
      for (int pp = 0; pp < 8; ++pp) {                                         \
        int ps_ = (t) * 64 + w * 8 + pp;                                       \
        int uu = us[ps_], vv = vs[ps_];                                        \
        float cnL = 0.f, aaL = 0.f, raL = 0.f;                                 \
        const uint32_t* ru = bits + (size_t)uu * roww;                         \
        const uint32_t* rv = bits + (size_t)vv * roww;                         \
        for (int wd = l; wd < roww; wd += 64) {                                \
          uint32_t c = ru[wd] & rv[wd];                                        \
          cnL += (float)__popc(c);                                             \
          while (c) {                                                          \
            int bb = __ffs(c) - 1;                                             \
            int idx = wd * 32 + bb;                                            \
            aaL += invlog[idx]; raL += invdeg[idx];                            \
            c &= c - 1;                                                        \
          }                                                                    \
        }                                                                      \
        _Pragma("unroll")                                                      \
        for (int off = 32; off; off >>= 1) {                                   \
          cnL += __shfl_xor(cnL, off);                                         \
          aaL += __shfl_xor(aaL, off);                                         \
          raL += __shfl_xor(raL, off);                                         \
        }                                                                      \
        if (l == 0) {                                                          \
          ushort* fq = feats + (w * 8 + pp) * FSTRIDE;                         \
          fq[513] = f2bf(cnL); fq[514] = f2bf(aaL); fq[515] = f2bf(raL);       \
        }                                                                      \
      }                                                                        \
    }                                                                          \
  }

  GATHER(0);
  WRITE_FEATS(0);
  __syncthreads();

  #pragma unroll
  for (int t = 0; t < 2; ++t) {
    // ---- GEMM1: feats[64x544] @ W1'[544x256]; wave w: n-tiles {2w,2w+1} ----
    f32x4 acc[4][2];
    #pragma unroll
    for (int m = 0; m < 4; ++m)
      #pragma unroll
      for (int i = 0; i < 2; ++i) acc[m][i] = (f32x4){0.f, 0.f, 0.f, 0.f};

    const ushort* aB = feats + lr * FSTRIDE + lk * 8;
    const ushort* bW = w1p + (size_t)(w * 2) * KS1 * 512 + l * 8;

    short8v bq[3][2];   // 2-deep rotating B prefetch (covers L2 latency)
    #pragma unroll
    for (int i = 0; i < 2; ++i) {
      bq[0][i] = *(const short8v*)(bW + (size_t)(i * KS1 + 0) * 512);
      bq[1][i] = *(const short8v*)(bW + (size_t)(i * KS1 + 1) * 512);
    }
    short8v aq[2][4];   // 1-deep A (ds_read) prefetch
    #pragma unroll
    for (int m = 0; m < 4; ++m)
      aq[0][m] = *(const short8v*)(aB + m * 16 * FSTRIDE + 0);

    #pragma unroll
    for (int ks = 0; ks < KS1; ++ks) {
      if (ks + 2 < KS1) {
        #pragma unroll
        for (int i = 0; i < 2; ++i)
          bq[(ks + 2) % 3][i] = *(const short8v*)(bW + (size_t)(i * KS1 + ks + 2) * 512);
      }
      if (ks + 1 < KS1) {
        #pragma unroll
        for (int m = 0; m < 4; ++m)
          aq[(ks + 1) & 1][m] = *(const short8v*)(aB + m * 16 * FSTRIDE + (ks + 1) * 32);
      }
      #pragma unroll
      for (int i = 0; i < 2; ++i)
        #pragma unroll
        for (int m = 0; m < 4; ++m)
          acc[m][i] = __builtin_amdgcn_mfma_f32_16x16x32_bf16(aq[ks & 1][m], bq[ks % 3][i], acc[m][i], 0, 0, 0);
    }

    uint32_t h1r[2][8];
    #pragma unroll
    for (int i = 0; i < 2; ++i) {
      float bias = b1[(w * 2 + i) * 16 + lr];
      #pragma unroll
      for (int m = 0; m < 4; ++m) {
        float v0 = fmaxf(acc[m][i][0] + bias, 0.f);
        float v1 = fmaxf(acc[m][i][1] + bias, 0.f);
        float v2 = fmaxf(acc[m][i][2] + bias, 0.f);
        float v3 = fmaxf(acc[m][i][3] + bias, 0.f);
        h1r[i][m * 2]     = pk2(v0, v1);
        h1r[i][m * 2 + 1] = pk2(v2, v3);
      }
    }
    __syncthreads();   // feats fully consumed

    ushort* h1 = feats;   // [row*H1S + col]
    #pragma unroll
    for (int i = 0; i < 2; ++i) {
      int col = (w * 2 + i) * 16 + lr;
      #pragma unroll
      for (int m = 0; m < 4; ++m) {
        int row0 = m * 16 + lk * 4;
        h1[(row0)     * H1S + col] = (ushort)(h1r[i][m * 2]);
        h1[(row0 + 1) * H1S + col] = (ushort)(h1r[i][m * 2] >> 16);
        h1[(row0 + 2) * H1S + col] = (ushort)(h1r[i][m * 2 + 1]);
        h1[(row0 + 3) * H1S + col] = (ushort)(h1r[i][m * 2 + 1] >> 16);
      }
    }
    __syncthreads();

    // issue next tile's gathers; they complete under GEMM2/GEMM3
    if (t == 0) GATHER(1);

    // ---- GEMM2: h1[64x256] @ W2[256x128]; wave w owns n-tile w ----
    f32x4 acc2[4];
    #pragma unroll
    for (int m = 0; m < 4; ++m) acc2[m] = (f32x4){0.f, 0.f, 0.f, 0.f};

    const ushort* aB2 = h1 + lr * H1S + lk * 8;
    const ushort* bW2 = w2p + (size_t)w * KS2 * 512 + l * 8;

    short8v b2f[2];
    b2f[0] = *(const short8v*)(bW2);

    #pragma unroll
    for (int ks = 0; ks < KS2; ++ks) {
      int cur = ks & 1, nxt = cur ^ 1;
      if (ks + 1 < KS2)
        b2f[nxt] = *(const short8v*)(bW2 + (size_t)(ks + 1) * 512);
      #pragma unroll
      for (int m = 0; m < 4; ++m) {
        short8v am = *(const short8v*)(aB2 + m * 16 * H1S + ks * 32);
        acc2[m] = __builtin_amdgcn_mfma_f32_16x16x32_bf16(am, b2f[cur], acc2[m], 0, 0, 0);
      }
    }

    ushort* h2 = feats + H2OFF;
    {
      int col = w * 16 + lr;
      float bias = b2[col];
      #pragma unroll
      for (int m = 0; m < 4; ++m) {
        int row0 = m * 16 + lk * 4;
        #pragma unroll
        for (int r = 0; r < 4; ++r)
          h2[(row0 + r) * H2S + col] = f2bf(fmaxf(acc2[m][r] + bias, 0.f));
      }
    }
    __syncthreads();

    // ---- GEMM3: h2[64x128] @ W3[128x1] ----
    {
      int p = tid >> 3, gg = tid & 7;
      const ushort* hp = h2 + p * H2S + gg * 16;
      float s = 0.f;
      #pragma unroll
      for (int j = 0; j < 16; ++j) s += bf2f(hp[j]) * W3[gg * 16 + j];
      s += __shfl_down(s, 4, 8);
      s += __shfl_down(s, 2, 8);
      s += __shfl_down(s, 1, 8);
      if (gg == 0) out[pb + t * 64 + p] = s + b3[0];
    }

    if (t == 0) {
      __syncthreads();      // h2 reads done; feats region reusable
      WRITE_FEATS(1);
      __syncthreads();
    }
  }
  #undef GATHER
  #undef WRITE_FEATS
}

extern "C" void kernel_launch(void* const* d_in, const int* in_sizes, int n_in,
                              void* d_out, int out_size, void* d_ws, size_t ws_size,
                              hipStream_t stream) {
  const float* x     = (const float*)d_in[0];
  const int*   ei    = (const int*)d_in[1];
  const int*   pairs = (const int*)d_in[2];
  const float* W1    = (const float*)d_in[3];
  const float* b1    = (const float*)d_in[4];
  const float* W2    = (const float*)d_in[5];
  const float* b2    = (const float*)d_in[6];
  const float* W3    = (const float*)d_in[7];
  const float* b3    = (const float*)d_in[8];
  float* out = (float*)d_out;

  int N = in_sizes[0] / IN_CH;       // 8192
  int E = in_sizes[1] / 2;           // 262144
  int P = in_sizes[2] / 2;           // 65536
  int roww = (N + 31) >> 5;          // 256

  char* wsb = (char*)d_ws;
  uint32_t* bits = (uint32_t*)wsb;                       size_t off = (size_t)N * roww * 4;
  float* invlog  = (float*)(wsb + off);                  off += (size_t)N * 4;
  float* invdeg  = (float*)(wsb + off);                  off += (size_t)N * 4;
  int*   deg     = (int*)(wsb + off);                    off += (size_t)N * 4;
  float* nrm     = (float*)(wsb + off);                  off += (size_t)N * 4;
  ushort* adjl   = (ushort*)(wsb + off);                 off += (size_t)N * CAP * 2;
  ushort* w1pack = (ushort*)(wsb + off);                 off += (size_t)T1PACK * 8 * 2;
  ushort* w2pack = (ushort*)(wsb + off);                 off += (size_t)T2PACK * 8 * 2;

  int nwords = N * roww;
  k_prep<<<1024, 256, 0, stream>>>(W1, W2, w1pack, w2pack, bits, nwords);
  k_build_adj<<<(E + 255) / 256, 256, 0, stream>>>(ei, E, roww, bits);
  k_node_lists<<<(N + 3) / 4, 256, 0, stream>>>(bits, x, N, roww, invlog, invdeg, deg, nrm, adjl);
  k_mlp6<<<P / 128, 512, 0, stream>>>(x, pairs, bits, roww, deg, nrm, invlog, invdeg, adjl,
                                      w1pack, b1, w2pack, b2, W3, b3, out, P);
}